// Round 2
// baseline (9640.705 us; speedup 1.0000x reference)
//
#include <hip/hip_runtime.h>
#include <hip/hip_bf16.h>

#define NN 50000
#define DD 512
#define KE 128
#define TJN 4
#define BNEPS 1e-5f

// dtype modes: 0 = fp32, 1 = bf16, 2 = use flags[0]
__device__ __forceinline__ float bf2f(unsigned short h){
  return __uint_as_float(((unsigned int)h) << 16);
}
__device__ __forceinline__ float load1(const void* p, long i, int bf){
  if (bf) return bf2f(((const unsigned short*)p)[i]);
  return ((const float*)p)[i];
}
__device__ __forceinline__ float4 load4(const void* p, long i, int bf){
  if (bf){
    ushort4 h = *(const ushort4*)((const unsigned short*)p + i);
    return make_float4(bf2f(h.x), bf2f(h.y), bf2f(h.z), bf2f(h.w));
  }
  return *(const float4*)((const float*)p + i);
}
__device__ __forceinline__ void store1(void* p, long i, int bf, float v){
  if (bf) ((__hip_bfloat16*)p)[i] = __float2bfloat16(v);
  else ((float*)p)[i] = v;
}

// ---------------- dtype sniffing ----------------
// flags[0]=1 if float inputs are bf16; flags[1]=1 if edge_index is int64.
__global__ void detect_kernel(const void* xraw, const void* eraw, int* flags){
  if (blockIdx.x == 0 && threadIdx.x == 0){
    const unsigned short* p = (const unsigned short*)xraw;
    int cnt = 0;
    for (int i = 0; i < 128; i++){
      int e = (p[i] >> 7) & 0xFF;
      if (e >= 110 && e <= 133) cnt++;   // bf16: ~all hit; fp32: ~55%
    }
    flags[0] = (cnt >= 96) ? 1 : 0;
    const unsigned int* q = (const unsigned int*)eraw;
    int z = 0;
    for (int i = 0; i < 64; i++) if (q[2*i+1] == 0u) z++;
    flags[1] = (z >= 48) ? 1 : 0;
  }
}

__global__ void cvt_f(const void* __restrict__ src, float* __restrict__ dst,
                      long n, const int* __restrict__ flags){
  int bf = flags[0];
  long i = (long)blockIdx.x * blockDim.x + threadIdx.x;
  long stride = (long)gridDim.x * blockDim.x;
  for (; i < n; i += stride) dst[i] = load1(src, i, bf);
}

// lin_W [TJ][D][S] -> W2 [D][TJ*S]  (c = t*128+s)
__global__ void cvt_linW(const void* __restrict__ src, float* __restrict__ dst,
                         const int* __restrict__ flags){
  int bf = flags[0];
  int i = blockIdx.x * blockDim.x + threadIdx.x;
  if (i >= TJN * DD * 128) return;
  int t = i / (DD * 128);
  int r = i - t * (DD * 128);
  int d = r >> 7, s = r & 127;
  dst[(long)d * DD + t * 128 + s] = load1(src, i, bf);
}

__global__ void cvt_idx(const void* __restrict__ src, int* __restrict__ dst,
                        long n, const int* __restrict__ flags){
  int w64 = flags[1];
  long i = (long)blockIdx.x * blockDim.x + threadIdx.x;
  long stride = (long)gridDim.x * blockDim.x;
  for (; i < n; i += stride)
    dst[i] = w64 ? (int)((const long long*)src)[i] : ((const int*)src)[i];
}

// ---------------- GCN pieces ----------------
__global__ void deg_kernel(const int* __restrict__ dst, float* __restrict__ deg, int E){
  int i = blockIdx.x * blockDim.x + threadIdx.x;
  if (i < E) atomicAdd(&deg[dst[i]], 1.0f);
}
__global__ void dinv_kernel(float* deg){
  int i = blockIdx.x * blockDim.x + threadIdx.x;
  if (i < NN) deg[i] = rsqrtf(deg[i] + 1.0f);
}

// xw is bf16 [N,D]; agg fp32 accumulated with atomics
__global__ __launch_bounds__(128) void gcn_agg(
    const int* __restrict__ srcv, const int* __restrict__ dstv,
    const float* __restrict__ dinv, const void* __restrict__ xw,
    float* __restrict__ agg){
  int e = blockIdx.x;
  int s = srcv[e], d = dstv[e];
  float nm = dinv[s] * dinv[d];
  int c = threadIdx.x * 4;
  float4 v = load4(xw, (long)s * DD + c, 1);
  float* o = &agg[(long)d * DD + c];
  atomicAdd(o + 0, nm * v.x);
  atomicAdd(o + 1, nm * v.y);
  atomicAdd(o + 2, nm * v.z);
  atomicAdd(o + 3, nm * v.w);
}

// agg = X + agg + dinv^2*xw + b
__global__ void gcn_self(const void* __restrict__ X, const void* __restrict__ xw,
                         const float* __restrict__ dinv, const float* __restrict__ b,
                         float* __restrict__ agg, const int* __restrict__ flags){
  int xf = flags[0];
  long i = (long)blockIdx.x * blockDim.x + threadIdx.x;
  long stride = (long)gridDim.x * blockDim.x;
  long n = (long)NN * DD;
  for (; i < n; i += stride){
    int nd = (int)(i >> 9);
    int c = (int)(i & 511);
    float di = dinv[nd];
    agg[i] = load1(X, i, xf) + agg[i] + di * di * load1(xw, i, 1) + b[c];
  }
}

// ---------------- batch norm ----------------
__global__ __launch_bounds__(512) void bn_stats(const float* __restrict__ T,
                                                float* __restrict__ sum,
                                                float* __restrict__ sumsq){
  int c = threadIdx.x;
  long r0 = (long)blockIdx.x * 128;
  float s = 0.f, q = 0.f;
  for (int r = 0; r < 128; r++){
    long rr = r0 + r;
    if (rr < NN){
      float v = T[rr * DD + c];
      s += v; q += v * v;
    }
  }
  atomicAdd(&sum[c], s);
  atomicAdd(&sumsq[c], q);
}

__global__ void bn_apply(const float* __restrict__ T,
                         const float* __restrict__ sum, const float* __restrict__ sumsq,
                         const float* __restrict__ g, const float* __restrict__ b,
                         const void* __restrict__ addsrc, int addmode,
                         void* __restrict__ out, int outmode,
                         const int* __restrict__ flags){
  int am = (addmode == 2) ? flags[0] : addmode;
  int om = (outmode == 2) ? flags[0] : outmode;
  long i = (long)blockIdx.x * blockDim.x + threadIdx.x;
  long stride = (long)gridDim.x * blockDim.x;
  long n = (long)NN * DD;
  const float invN = 1.0f / (float)NN;
  for (; i < n; i += stride){
    int c = (int)(i & 511);
    float m = sum[c] * invN;
    float var = sumsq[c] * invN - m * m;
    float v = (T[i] - m) * rsqrtf(var + BNEPS) * g[c] + b[c];
    if (addsrc) v += load1(addsrc, i, am);
    store1(out, i, om, v);
  }
}

// ---------------- small elementwise ----------------
__global__ void scale_sig(float* __restrict__ U, const float* __restrict__ filt){
  int i = blockIdx.x * blockDim.x + threadIdx.x;
  if (i < KE * DD){
    int k = i >> 9;
    int c = i & 511;
    U[i] *= filt[k * TJN + (c >> 7)];
  }
}

__global__ void zero_out_bf16(void* out, long nbytes){
  long i = (long)blockIdx.x * blockDim.x + threadIdx.x;
  long stride = (long)gridDim.x * blockDim.x;
  long n = nbytes / 2;
  for (; i < n; i += stride) ((unsigned short*)out)[i] = 0;
}

// ---------------- GEMM: C = act(A@B + bias) (+ addsrc) ----------------
// A: amode dtype; B: fp32 always; C: cmode dtype. 128x128 tile, BK=16.
__global__ __launch_bounds__(256) void sgemm_nn(
    const void* __restrict__ A, const float* __restrict__ B, void* __restrict__ C,
    int M, int N, int Kd, int lda, int ldb, int ldc,
    const float* __restrict__ bias, const void* __restrict__ addsrc, int dorelu,
    int amode, int addmode, int cmode, const int* __restrict__ flags){
  int fl = flags[0];
  int abf = (amode == 2) ? fl : amode;
  int adbf = (addmode == 2) ? fl : addmode;
  int cbf = (cmode == 2) ? fl : cmode;
  __shared__ float As[16][132];
  __shared__ float Bs[16][132];
  const int tid = threadIdx.x;
  const int bm = blockIdx.y * 128;
  const int bn = blockIdx.x * 128;
  const int lane = tid & 63, wave = tid >> 6;
  const int tm0 = wave * 32 + ((lane >> 4) << 3);
  const int tn0 = (lane & 15) << 3;
  float acc[8][8];
#pragma unroll
  for (int i = 0; i < 8; i++)
#pragma unroll
    for (int j = 0; j < 8; j++) acc[i][j] = 0.f;

  for (int k0 = 0; k0 < Kd; k0 += 16){
    __syncthreads();
#pragma unroll
    for (int i = 0; i < 2; i++){
      int idx4 = tid + i * 256;
      int kk4 = idx4 & 3, r = idx4 >> 2;          // A: 128 rows x 16 k
      float4 v = make_float4(0.f, 0.f, 0.f, 0.f);
      int row = bm + r;
      if (row < M) v = load4(A, (long)row * lda + k0 + kk4 * 4, abf);
      As[kk4 * 4 + 0][r] = v.x;
      As[kk4 * 4 + 1][r] = v.y;
      As[kk4 * 4 + 2][r] = v.z;
      As[kk4 * 4 + 3][r] = v.w;
      int c4 = idx4 & 31, kk = idx4 >> 5;         // B: 16 k x 128 cols
      float4 w = *(const float4*)&B[(long)(k0 + kk) * ldb + bn + c4 * 4];
      *(float4*)&Bs[kk][c4 * 4] = w;
    }
    __syncthreads();
#pragma unroll
    for (int kk = 0; kk < 16; kk++){
      float a[8], b[8];
#pragma unroll
      for (int j = 0; j < 8; j++) a[j] = As[kk][tm0 + j];
#pragma unroll
      for (int j = 0; j < 8; j++) b[j] = Bs[kk][tn0 + j];
#pragma unroll
      for (int i = 0; i < 8; i++)
#pragma unroll
        for (int j = 0; j < 8; j++) acc[i][j] += a[i] * b[j];
    }
  }
#pragma unroll
  for (int i = 0; i < 8; i++){
    int row = bm + tm0 + i;
    if (row < M){
#pragma unroll
      for (int j = 0; j < 8; j++){
        int col = bn + tn0 + j;
        float v = acc[i][j];
        if (bias) v += bias[col];
        if (dorelu) v = fmaxf(v, 0.f);
        if (addsrc) v += load1(addsrc, (long)row * ldc + col, adbf);
        store1(C, (long)row * ldc + col, cbf, v);
      }
    }
  }
}

// ---------------- split-K: C[128x512] += A^T @ B (atomics) ----------------
__global__ __launch_bounds__(256) void sgemm_tn_atomic(
    const void* __restrict__ A, const void* __restrict__ B, float* __restrict__ C,
    int Kt, int lda, int ldb, int ldc, int kchunk,
    int amode, int bmode, const int* __restrict__ flags){
  int fl = flags[0];
  int abf = (amode == 2) ? fl : amode;
  int bbf = (bmode == 2) ? fl : bmode;
  __shared__ float As[32][33];
  __shared__ float Bs[32][132];
  const int tid = threadIdx.x;
  const int bm = blockIdx.y * 32;
  const int bn = blockIdx.x * 128;
  const int k0 = blockIdx.z * kchunk;
  const int kend = min(k0 + kchunk, Kt);
  const int tn0 = (tid & 31) * 4;
  const int tm0 = (tid >> 5) * 4;
  float acc[4][4];
#pragma unroll
  for (int i = 0; i < 4; i++)
#pragma unroll
    for (int j = 0; j < 4; j++) acc[i][j] = 0.f;

  for (int kb = k0; kb < kend; kb += 32){
    __syncthreads();
    {
      int c4 = tid & 7, r = tid >> 3;
      float4 v = make_float4(0.f, 0.f, 0.f, 0.f);
      if (kb + r < kend) v = load4(A, (long)(kb + r) * lda + bm + c4 * 4, abf);
      As[r][c4 * 4 + 0] = v.x;
      As[r][c4 * 4 + 1] = v.y;
      As[r][c4 * 4 + 2] = v.z;
      As[r][c4 * 4 + 3] = v.w;
    }
#pragma unroll
    for (int i = 0; i < 4; i++){
      int idx4 = tid + i * 256;
      int c4 = idx4 & 31, r = idx4 >> 5;
      float4 v = make_float4(0.f, 0.f, 0.f, 0.f);
      if (kb + r < kend) v = load4(B, (long)(kb + r) * ldb + bn + c4 * 4, bbf);
      *(float4*)&Bs[r][c4 * 4] = v;
    }
    __syncthreads();
#pragma unroll
    for (int r = 0; r < 32; r++){
      float a[4], b[4];
#pragma unroll
      for (int j = 0; j < 4; j++) a[j] = As[r][tm0 + j];
#pragma unroll
      for (int j = 0; j < 4; j++) b[j] = Bs[r][tn0 + j];
#pragma unroll
      for (int i = 0; i < 4; i++)
#pragma unroll
        for (int j = 0; j < 4; j++) acc[i][j] += a[i] * b[j];
    }
  }
#pragma unroll
  for (int i = 0; i < 4; i++)
#pragma unroll
    for (int j = 0; j < 4; j++)
      atomicAdd(&C[(long)(bm + tm0 + i) * ldc + bn + tn0 + j], acc[i][j]);
}

// ---------------- host orchestration ----------------
extern "C" void kernel_launch(void* const* d_in, const int* in_sizes, int n_in,
                              void* d_out, int out_size, void* d_ws, size_t ws_size,
                              hipStream_t stream){
  const int E = in_sizes[1] / 2;
  const long NB = (long)NN * DD;             // 25.6M elements
  float* ws = (float*)d_ws;
  (void)n_in;

  size_t cur = 0;
  auto alloc = [&](size_t n){ size_t o = cur; cur += (n + 63) & ~(size_t)63; return o; };

  size_t o_flags = alloc(64);
  size_t o_zero  = cur;                      // ---- zeroed region ----
  size_t o_dinv  = alloc(NN);
  size_t o_U     = alloc((size_t)KE * DD);
  size_t o_U2    = alloc((size_t)KE * DD);
  size_t o_stats = alloc(6 * DD);
  size_t zlen    = cur - o_zero;             // -----------------------
  size_t o_filt  = alloc(KE * TJN);
  size_t o_bgcn  = alloc(DD);
  size_t o_b2    = alloc(DD);
  size_t o_bfus  = alloc(DD);
  size_t o_bff1  = alloc(2 * DD);
  size_t o_bff2  = alloc(DD);
  size_t o_bn    = alloc(6 * DD);
  size_t o_Wg    = alloc((size_t)DD * DD);
  size_t o_W2    = alloc((size_t)DD * DD);
  size_t o_Wf    = alloc((size_t)DD * DD);
  size_t o_W1    = alloc((size_t)DD * 2 * DD);
  size_t o_Wff2  = alloc((size_t)2 * DD * DD);
  size_t o_idx   = alloc((size_t)2 * E);         // int32 slots
  size_t o_BF    = alloc(NB);                    // fp32 N x D
  size_t o_BA    = alloc(NB / 2);                // bf16 N x D (xw/HT/COMB)
  size_t o_BHL   = alloc(NB / 2);                // bf16 N x D (h_local); BA+BHL = F1

  if (cur * 4 > ws_size){                        // graceful fail, no OOB
    zero_out_bf16<<<2048, 256, 0, stream>>>(d_out, (long)out_size * 2);
    return;
  }

  int* flags  = (int*)(ws + o_flags);
  float* BF   = ws + o_BF;
  void*  BA   = (void*)(ws + o_BA);
  void*  BHL  = (void*)(ws + o_BHL);
  void*  F1   = BA;                              // bf16 [N,1024] spans BA+BHL
  int* srcv   = (int*)(ws + o_idx);
  int* dstv   = srcv + E;
  float* dinv = ws + o_dinv;
  float* U    = ws + o_U;
  float* U2   = ws + o_U2;
  float* st   = ws + o_stats;

  detect_kernel<<<1, 64, 0, stream>>>(d_in[0], d_in[1], flags);
  hipMemsetAsync(ws + o_zero, 0, zlen * 4, stream);
  hipMemsetAsync(BF, 0, NB * 4, stream);         // agg accumulator

  auto cvt = [&](int idx, size_t off, long n){
    int blocks = (int)((n + 255) / 256); if (blocks > 4096) blocks = 4096;
    cvt_f<<<blocks, 256, 0, stream>>>(d_in[idx], ws + off, n, flags);
  };
  cvt(3,  o_filt, KE * TJN);
  cvt(4,  o_Wg,  (long)DD * DD);
  cvt(5,  o_bgcn, DD);
  cvt_linW<<<(TJN * DD * 128 + 255) / 256, 256, 0, stream>>>(d_in[6], ws + o_W2, flags);
  cvt(7,  o_b2,  DD);
  cvt(8,  o_Wf,  (long)DD * DD);
  cvt(9,  o_bfus, DD);
  for (int i = 0; i < 6; i++) cvt(10 + i, o_bn + i * DD, DD);
  cvt(16, o_W1,  (long)DD * 2 * DD);
  cvt(17, o_bff1, 2 * DD);
  cvt(18, o_Wff2, (long)2 * DD * DD);
  cvt(19, o_bff2, DD);
  cvt_idx<<<4096, 256, 0, stream>>>(d_in[1], srcv, 2L * E, flags);

  const int MT = (NN + 127) / 128;   // 391
  dim3 g512(DD / 128, MT), blk(256);
  const float* X  = nullptr;  // raw d_in[0], flag dtype
  const void* Xr  = d_in[0];
  const void* EVr = d_in[2];
  (void)X;

  // ---- local GCN branch ----
  sgemm_nn<<<g512, blk, 0, stream>>>(Xr, ws + o_Wg, BA, NN, DD, DD, DD, DD, DD,
                                     nullptr, nullptr, 0, 2, 0, 1, flags);   // xw (bf16)
  deg_kernel<<<(E + 255) / 256, 256, 0, stream>>>(dstv, dinv, E);
  dinv_kernel<<<(NN + 255) / 256, 256, 0, stream>>>(dinv);
  gcn_agg<<<E, 128, 0, stream>>>(srcv, dstv, dinv, BA, BF);
  gcn_self<<<4096, 256, 0, stream>>>(Xr, BA, dinv, ws + o_bgcn, BF, flags);
  bn_stats<<<MT, 512, 0, stream>>>(BF, st + 0, st + DD);
  bn_apply<<<4096, 256, 0, stream>>>(BF, st + 0, st + DD,
                                     ws + o_bn + 0 * DD, ws + o_bn + 1 * DD,
                                     nullptr, 0, BHL, 1, flags);             // h_local bf16

  // ---- global WaveGC branch ----
  sgemm_nn<<<g512, blk, 0, stream>>>(Xr, ws + o_W2, BA, NN, DD, DD, DD, DD, DD,
                                     ws + o_b2, nullptr, 0, 2, 0, 1, flags); // HT bf16
  sgemm_tn_atomic<<<dim3(4, 4, 25), blk, 0, stream>>>(EVr, BA, U, NN, KE, DD, DD,
                                                      2048, 2, 1, flags);
  scale_sig<<<(KE * DD) / 256, 256, 0, stream>>>(U, ws + o_filt);
  sgemm_nn<<<g512, blk, 0, stream>>>(EVr, U, BF, NN, DD, KE, KE, DD, DD,
                                     nullptr, nullptr, 1, 2, 0, 0, flags);   // V fp32
  sgemm_tn_atomic<<<dim3(4, 4, 25), blk, 0, stream>>>(EVr, BF, U2, NN, KE, DD, DD,
                                                      2048, 2, 0, flags);
  scale_sig<<<(KE * DD) / 256, 256, 0, stream>>>(U2, ws + o_filt);
  sgemm_nn<<<g512, blk, 0, stream>>>(EVr, U2, BA, NN, DD, KE, KE, DD, DD,
                                     nullptr, nullptr, 0, 2, 0, 1, flags);   // COMB bf16
  sgemm_nn<<<g512, blk, 0, stream>>>(BA, ws + o_Wf, BF, NN, DD, DD, DD, DD, DD,
                                     ws + o_bfus, Xr, 1, 1, 2, 0, flags);    // relu+X, fp32
  bn_stats<<<MT, 512, 0, stream>>>(BF, st + 2 * DD, st + 3 * DD);
  bn_apply<<<4096, 256, 0, stream>>>(BF, st + 2 * DD, st + 3 * DD,
                                     ws + o_bn + 2 * DD, ws + o_bn + 3 * DD,
                                     BHL, 1, BF, 0, flags);                  // h = bn+hl (in-place fp32)

  // ---- FFN ----
  sgemm_nn<<<dim3(2 * DD / 128, MT), blk, 0, stream>>>(
      BF, ws + o_W1, F1, NN, 2 * DD, DD, DD, 2 * DD, 2 * DD,
      ws + o_bff1, nullptr, 1, 0, 0, 1, flags);                              // F1 bf16
  sgemm_nn<<<g512, blk, 0, stream>>>(F1, ws + o_Wff2, BF, NN, DD, 2 * DD,
                                     2 * DD, DD, DD,
                                     ws + o_bff2, BF, 0, 1, 0, 0, flags);    // ff2 + h (in-place)
  bn_stats<<<MT, 512, 0, stream>>>(BF, st + 4 * DD, st + 5 * DD);
  bn_apply<<<4096, 256, 0, stream>>>(BF, st + 4 * DD, st + 5 * DD,
                                     ws + o_bn + 4 * DD, ws + o_bn + 5 * DD,
                                     nullptr, 0, d_out, 2, flags);           // -> out
}

// Round 3
// 2272.404 us; speedup vs baseline: 4.2425x; 4.2425x over previous
//
#include <hip/hip_runtime.h>
#include <hip/hip_bf16.h>

#define NN 50000
#define DD 512
#define KE 128
#define TJN 4
#define BNEPS 1e-5f

typedef __attribute__((ext_vector_type(8))) short short8;
typedef __attribute__((ext_vector_type(4))) float floatx4;

// dtype modes: 0 = fp32, 1 = bf16, 2 = use flags[0]
__device__ __forceinline__ float bf2f(unsigned short h){
  return __uint_as_float(((unsigned int)h) << 16);
}
__device__ __forceinline__ unsigned short f2bf(float f){
  unsigned int u = __float_as_uint(f);
  unsigned int r = (u + 0x7FFF + ((u >> 16) & 1)) >> 16;
  return (unsigned short)r;
}
__device__ __forceinline__ float load1(const void* p, long i, int bf){
  if (bf) return bf2f(((const unsigned short*)p)[i]);
  return ((const float*)p)[i];
}
__device__ __forceinline__ void store1(void* p, long i, int bf, float v){
  if (bf) ((unsigned short*)p)[i] = f2bf(v);
  else ((float*)p)[i] = v;
}

// ---------------- dtype sniffing ----------------
__global__ void detect_kernel(const void* xraw, const void* eraw, int* flags){
  if (blockIdx.x == 0 && threadIdx.x == 0){
    const unsigned short* p = (const unsigned short*)xraw;
    int cnt = 0;
    for (int i = 0; i < 128; i++){
      int e = (p[i] >> 7) & 0xFF;
      if (e >= 110 && e <= 133) cnt++;
    }
    flags[0] = (cnt >= 96) ? 1 : 0;
    const unsigned int* q = (const unsigned int*)eraw;
    int z = 0;
    for (int i = 0; i < 64; i++) if (q[2*i+1] == 0u) z++;
    flags[1] = (z >= 48) ? 1 : 0;
  }
}

__global__ void cvt_f(const void* __restrict__ src, float* __restrict__ dst,
                      long n, const int* __restrict__ flags){
  int bf = flags[0];
  long i = (long)blockIdx.x * blockDim.x + threadIdx.x;
  long stride = (long)gridDim.x * blockDim.x;
  for (; i < n; i += stride) dst[i] = load1(src, i, bf);
}

// transpose weight to bf16 [Nc][K]: dst[n*K+k] = src[k*Nc+n]
__global__ void cvt_wt(const void* __restrict__ src, unsigned short* __restrict__ dst,
                       int K, int Nc, const int* __restrict__ flags){
  int bf = flags[0];
  long n = (long)K * Nc;
  long i = (long)blockIdx.x * blockDim.x + threadIdx.x;
  long stride = (long)gridDim.x * blockDim.x;
  for (; i < n; i += stride){
    int k = (int)(i / Nc), c = (int)(i - (long)k * Nc);
    dst[(long)c * K + k] = f2bf(load1(src, i, bf));
  }
}

// lin_W [TJ][D][S] -> Bt[(t*128+s)][d] bf16
__global__ void cvt_linW(const void* __restrict__ src, unsigned short* __restrict__ dst,
                         const int* __restrict__ flags){
  int bf = flags[0];
  int i = blockIdx.x * blockDim.x + threadIdx.x;
  if (i >= TJN * DD * 128) return;
  int t = i / (DD * 128);
  int r = i - t * (DD * 128);
  int d = r >> 7, s = r & 127;
  dst[(long)((t << 7) + s) * DD + d] = f2bf(load1(src, i, bf));
}

__global__ void cvt_idx(const void* __restrict__ src, int* __restrict__ dst,
                        long n, const int* __restrict__ flags){
  int w64 = flags[1];
  long i = (long)blockIdx.x * blockDim.x + threadIdx.x;
  long stride = (long)gridDim.x * blockDim.x;
  for (; i < n; i += stride)
    dst[i] = w64 ? (int)((const long long*)src)[i] : ((const int*)src)[i];
}

// ---------------- CSR build ----------------
__global__ void deg_kernel(const int* __restrict__ dst, int* __restrict__ deg, int E){
  int i = blockIdx.x * blockDim.x + threadIdx.x;
  if (i < E) atomicAdd(&deg[dst[i]], 1);
}

__global__ __launch_bounds__(1024) void scan_kernel(const int* __restrict__ deg,
                                                    int* __restrict__ rowptr, int E){
  __shared__ int lds[1024];
  int t = threadIdx.x;
  const int CH = (NN + 1023) / 1024;   // 49
  int base = t * CH;
  int s = 0;
  for (int i = 0; i < CH; i++){
    int idx = base + i;
    if (idx < NN) s += deg[idx];
  }
  lds[t] = s;
  __syncthreads();
  for (int off = 1; off < 1024; off <<= 1){
    int v = (t >= off) ? lds[t - off] : 0;
    __syncthreads();
    lds[t] += v;
    __syncthreads();
  }
  int ex = (t == 0) ? 0 : lds[t - 1];
  for (int i = 0; i < CH; i++){
    int idx = base + i;
    if (idx < NN){ rowptr[idx] = ex; ex += deg[idx]; }
  }
  if (t == 1023) rowptr[NN] = ex;
}

__global__ void dinv_kernel(const int* __restrict__ deg, float* __restrict__ dinv){
  int i = blockIdx.x * blockDim.x + threadIdx.x;
  if (i < NN) dinv[i] = rsqrtf((float)deg[i] + 1.0f);
}

__global__ void scatter_kernel(const int* __restrict__ srcv, const int* __restrict__ dstv,
                               const int* __restrict__ rowptr, int* __restrict__ cursor,
                               int* __restrict__ csr, int E){
  int i = blockIdx.x * blockDim.x + threadIdx.x;
  if (i < E){
    int d = dstv[i];
    int pos = atomicAdd(&cursor[d], 1);
    csr[rowptr[d] + pos] = srcv[i];
  }
}

// ---------------- fused GCN gather (agg + self-loop + residual + bias) ----------------
__global__ __launch_bounds__(64) void gcn_gather(
    const int* __restrict__ rowptr, const int* __restrict__ csr,
    const float* __restrict__ dinv, const void* __restrict__ xw /*bf16*/,
    const void* __restrict__ X, const float* __restrict__ bias,
    float* __restrict__ out, const int* __restrict__ flags){
  int d = blockIdx.x;
  int lane = threadIdx.x;
  __shared__ int s_idx[64];
  __shared__ float s_dv[64];
  int start = rowptr[d], end = rowptr[d + 1];
  float dd = dinv[d];
  float acc[8];
#pragma unroll
  for (int k = 0; k < 8; k++) acc[k] = 0.f;
  const unsigned short* xwp = (const unsigned short*)xw;
  int c0 = lane * 8;
  for (int j0 = start; j0 < end; j0 += 64){
    int cnt = min(64, end - j0);
    __syncthreads();
    if (lane < cnt){
      int s = csr[j0 + lane];
      s_idx[lane] = s;
      s_dv[lane] = dinv[s];
    }
    __syncthreads();
    for (int t = 0; t < cnt; t++){
      int s = s_idx[t];
      float nm = dd * s_dv[t];
      union { float4 f; unsigned short u[8]; } r;
      r.f = *(const float4*)(xwp + (long)s * DD + c0);
#pragma unroll
      for (int k = 0; k < 8; k++) acc[k] += nm * bf2f(r.u[k]);
    }
  }
  int xf = flags[0];
  long base = (long)d * DD + c0;
  union { float4 f; unsigned short u[8]; } sf;
  sf.f = *(const float4*)(xwp + base);
  float d2 = dd * dd;
#pragma unroll
  for (int k = 0; k < 8; k++)
    out[base + k] = load1(X, base + k, xf) + acc[k] + d2 * bf2f(sf.u[k]) + bias[c0 + k];
}

// ---------------- batch norm ----------------
__global__ __launch_bounds__(512) void bn_stats(const float* __restrict__ T,
                                                float* __restrict__ sum,
                                                float* __restrict__ sumsq){
  int c = threadIdx.x;
  long r0 = (long)blockIdx.x * 128;
  float s = 0.f, q = 0.f;
  for (int r = 0; r < 128; r++){
    long rr = r0 + r;
    if (rr < NN){
      float v = T[rr * DD + c];
      s += v; q += v * v;
    }
  }
  atomicAdd(&sum[c], s);
  atomicAdd(&sumsq[c], q);
}

__global__ void bn_apply(const float* __restrict__ T,
                         const float* __restrict__ sum, const float* __restrict__ sumsq,
                         const float* __restrict__ g, const float* __restrict__ b,
                         const void* __restrict__ addsrc, int addmode,
                         void* __restrict__ out, int outmode,
                         const int* __restrict__ flags){
  int am = (addmode == 2) ? flags[0] : addmode;
  int om = (outmode == 2) ? flags[0] : outmode;
  long i = (long)blockIdx.x * blockDim.x + threadIdx.x;
  long stride = (long)gridDim.x * blockDim.x;
  long n = (long)NN * DD;
  const float invN = 1.0f / (float)NN;
  for (; i < n; i += stride){
    int c = (int)(i & 511);
    float m = sum[c] * invN;
    float var = sumsq[c] * invN - m * m;
    float v = (T[i] - m) * rsqrtf(var + BNEPS) * g[c] + b[c];
    if (addsrc) v += load1(addsrc, i, am);
    store1(out, i, om, v);
  }
}

// scale by sig and emit transposed bf16 [DD][KE]
__global__ void scale_sig_t(const float* __restrict__ U, const float* __restrict__ filt,
                            unsigned short* __restrict__ Ut){
  int i = blockIdx.x * blockDim.x + threadIdx.x;
  if (i < KE * DD){
    int k = i >> 9;
    int c = i & 511;
    float v = U[i] * filt[k * TJN + (c >> 7)];
    Ut[(long)c * KE + k] = f2bf(v);
  }
}

__global__ void zero_out_bf16(void* out, long nbytes){
  long i = (long)blockIdx.x * blockDim.x + threadIdx.x;
  long stride = (long)gridDim.x * blockDim.x;
  long n = nbytes / 2;
  for (; i < n; i += stride) ((unsigned short*)out)[i] = 0;
}

// ---------------- MFMA bf16 GEMM: C = act(A@Bt^T + bias) (+ addsrc) ----------------
// A [M][Kd] (amode dtype); Bt bf16 [N][Kd]; 128x128 tile, BK=32, 4 waves (2x2 of 64x64).
#define LDSS 40   // LDS row stride in shorts (32 data + 8 pad; keeps 16B align, 2-way banks)
__global__ __launch_bounds__(256) void gemm_mfma(
    const void* __restrict__ A, const unsigned short* __restrict__ Bt,
    void* __restrict__ C, int M, int N, int Kd, int lda, int ldc,
    const float* __restrict__ bias, const void* __restrict__ addsrc, int dorelu,
    int amode, int addmode, int cmode, const int* __restrict__ flags){
  int fl = flags[0];
  int abf = (amode == 2) ? fl : amode;
  int adbf = (addmode == 2) ? fl : addmode;
  int cbf = (cmode == 2) ? fl : cmode;
  __shared__ unsigned short Asl[128 * LDSS];
  __shared__ unsigned short Bsl[128 * LDSS];
  const int tid = threadIdx.x;
  const int bm = blockIdx.y * 128, bn = blockIdx.x * 128;
  const int lane = tid & 63, wave = tid >> 6;
  const int wm = (wave & 1) * 64, wn = (wave >> 1) * 64;
  const int q = lane >> 4, l16 = lane & 15;
  floatx4 acc[4][4];
#pragma unroll
  for (int i = 0; i < 4; i++)
#pragma unroll
    for (int j = 0; j < 4; j++)
#pragma unroll
      for (int r = 0; r < 4; r++) acc[i][j][r] = 0.f;

  for (int k0 = 0; k0 < Kd; k0 += 32){
    __syncthreads();
#pragma unroll
    for (int p = 0; p < 2; p++){
      int idx = tid + p * 256;              // 512 chunks of 8 shorts each
      int r = idx >> 2, c8 = (idx & 3) * 8;
      int row = bm + r;
      float4 v = make_float4(0.f, 0.f, 0.f, 0.f);
      if (row < M){
        long off = (long)row * lda + k0 + c8;
        if (abf){
          v = *(const float4*)((const unsigned short*)A + off);
        } else {
          float4 f0 = *(const float4*)((const float*)A + off);
          float4 f1 = *(const float4*)((const float*)A + off + 4);
          union { float4 f; unsigned short u[8]; } pk;
          pk.u[0] = f2bf(f0.x); pk.u[1] = f2bf(f0.y);
          pk.u[2] = f2bf(f0.z); pk.u[3] = f2bf(f0.w);
          pk.u[4] = f2bf(f1.x); pk.u[5] = f2bf(f1.y);
          pk.u[6] = f2bf(f1.z); pk.u[7] = f2bf(f1.w);
          v = pk.f;
        }
      }
      *(float4*)&Asl[r * LDSS + c8] = v;
      float4 w = *(const float4*)(Bt + (long)(bn + r) * Kd + k0 + c8);
      *(float4*)&Bsl[r * LDSS + c8] = w;
    }
    __syncthreads();
    short8 af[4], bfr[4];
#pragma unroll
    for (int i = 0; i < 4; i++)
      af[i] = *(const short8*)&Asl[(wm + i * 16 + l16) * LDSS + q * 8];
#pragma unroll
    for (int j = 0; j < 4; j++)
      bfr[j] = *(const short8*)&Bsl[(wn + j * 16 + l16) * LDSS + q * 8];
#pragma unroll
    for (int i = 0; i < 4; i++)
#pragma unroll
      for (int j = 0; j < 4; j++)
        acc[i][j] = __builtin_amdgcn_mfma_f32_16x16x32_bf16(af[i], bfr[j], acc[i][j], 0, 0, 0);
  }
  // epilogue: C/D layout col=lane&15, row=quad*4+reg (m89/m91-verified)
#pragma unroll
  for (int i = 0; i < 4; i++){
#pragma unroll
    for (int r = 0; r < 4; r++){
      int row = bm + wm + i * 16 + q * 4 + r;
      if (row >= M) continue;
#pragma unroll
      for (int j = 0; j < 4; j++){
        int col = bn + wn + j * 16 + l16;
        float v = acc[i][j][r];
        if (bias) v += bias[col];
        if (dorelu) v = fmaxf(v, 0.f);
        if (addsrc) v += load1(addsrc, (long)row * ldc + col, adbf);
        store1(C, (long)row * ldc + col, cbf, v);
      }
    }
  }
}

// ---------------- split-K: C[128x512] += A^T @ B (atomics, SIMD fp32) ----------------
__device__ __forceinline__ float4 load4m(const void* p, long i, int bf){
  if (bf){
    union { float4 f; unsigned short u[8]; } r;
    r.f = *(const float4*)((const unsigned short*)p + i);   // only first 8B used? no:
    // we need 4 elements: read as ushort4
    ushort4 h = *(const ushort4*)((const unsigned short*)p + i);
    return make_float4(bf2f(h.x), bf2f(h.y), bf2f(h.z), bf2f(h.w));
  }
  return *(const float4*)((const float*)p + i);
}

__global__ __launch_bounds__(256) void sgemm_tn_atomic(
    const void* __restrict__ A, const void* __restrict__ B, float* __restrict__ C,
    int Kt, int lda, int ldb, int ldc, int kchunk,
    int amode, int bmode, const int* __restrict__ flags){
  int fl = flags[0];
  int abf = (amode == 2) ? fl : amode;
  int bbf = (bmode == 2) ? fl : bmode;
  __shared__ float As[32][33];
  __shared__ float Bs[32][132];
  const int tid = threadIdx.x;
  const int bm = blockIdx.y * 32;
  const int bn = blockIdx.x * 128;
  const int k0 = blockIdx.z * kchunk;
  const int kend = min(k0 + kchunk, Kt);
  const int tn0 = (tid & 31) * 4;
  const int tm0 = (tid >> 5) * 4;
  float acc[4][4];
#pragma unroll
  for (int i = 0; i < 4; i++)
#pragma unroll
    for (int j = 0; j < 4; j++) acc[i][j] = 0.f;

  for (int kb = k0; kb < kend; kb += 32){
    __syncthreads();
    {
      int c4 = tid & 7, r = tid >> 3;
      float4 v = make_float4(0.f, 0.f, 0.f, 0.f);
      if (kb + r < kend) v = load4m(A, (long)(kb + r) * lda + bm + c4 * 4, abf);
      As[r][c4 * 4 + 0] = v.x;
      As[r][c4 * 4 + 1] = v.y;
      As[r][c4 * 4 + 2] = v.z;
      As[r][c4 * 4 + 3] = v.w;
    }
#pragma unroll
    for (int i = 0; i < 4; i++){
      int idx4 = tid + i * 256;
      int c4 = idx4 & 31, r = idx4 >> 5;
      float4 v = make_float4(0.f, 0.f, 0.f, 0.f);
      if (kb + r < kend) v = load4m(B, (long)(kb + r) * ldb + bn + c4 * 4, bbf);
      *(float4*)&Bs[r][c4 * 4] = v;
    }
    __syncthreads();
#pragma unroll
    for (int r = 0; r < 32; r++){
      float a[4], b[4];
#pragma unroll
      for (int j = 0; j < 4; j++) a[j] = As[r][tm0 + j];
#pragma unroll
      for (int j = 0; j < 4; j++) b[j] = Bs[r][tn0 + j];
#pragma unroll
      for (int i = 0; i < 4; i++)
#pragma unroll
        for (int j = 0; j < 4; j++) acc[i][j] += a[i] * b[j];
    }
  }
#pragma unroll
  for (int i = 0; i < 4; i++)
#pragma unroll
    for (int j = 0; j < 4; j++)
      atomicAdd(&C[(long)(bm + tm0 + i) * ldc + bn + tn0 + j], acc[i][j]);
}

// ---------------- host orchestration ----------------
extern "C" void kernel_launch(void* const* d_in, const int* in_sizes, int n_in,
                              void* d_out, int out_size, void* d_ws, size_t ws_size,
                              hipStream_t stream){
  const int E = in_sizes[1] / 2;
  const long NB = (long)NN * DD;
  float* ws = (float*)d_ws;
  (void)n_in;

  size_t cur = 0;
  auto alloc = [&](size_t n){ size_t o = cur; cur += (n + 63) & ~(size_t)63; return o; };

  size_t o_flags = alloc(64);
  size_t o_zero  = cur;                      // ---- zeroed region ----
  size_t o_U     = alloc((size_t)KE * DD);
  size_t o_U2    = alloc((size_t)KE * DD);
  size_t o_stats = alloc(6 * DD);
  size_t o_ideg  = alloc(NN);
  size_t o_cur   = alloc(NN);
  size_t zlen    = cur - o_zero;             // -----------------------
  size_t o_dinv  = alloc(NN);
  size_t o_rowp  = alloc(NN + 64);
  size_t o_filt  = alloc(KE * TJN);
  size_t o_bgcn  = alloc(DD);
  size_t o_b2    = alloc(DD);
  size_t o_bfus  = alloc(DD);
  size_t o_bff1  = alloc(2 * DD);
  size_t o_bff2  = alloc(DD);
  size_t o_bn    = alloc(6 * DD);
  size_t o_Wgt   = alloc((size_t)DD * DD / 2);      // bf16 transposed weights
  size_t o_W2t   = alloc((size_t)DD * DD / 2);
  size_t o_Wft   = alloc((size_t)DD * DD / 2);
  size_t o_W1t   = alloc((size_t)DD * DD);          // [1024][512] bf16
  size_t o_Wff2t = alloc((size_t)DD * DD);          // [512][1024] bf16
  size_t o_Ut    = alloc((size_t)KE * DD / 2);
  size_t o_U2t   = alloc((size_t)KE * DD / 2);
  size_t o_idx   = alloc((size_t)2 * E);
  size_t o_csr   = alloc((size_t)E);
  size_t o_BF    = alloc(NB);                       // fp32 N x D
  size_t o_BA    = alloc(NB / 2);                   // bf16 N x D
  size_t o_BHL   = alloc(NB / 2);                   // bf16 N x D; BA+BHL = F1 [N,1024]

  if (cur * 4 > ws_size){
    zero_out_bf16<<<2048, 256, 0, stream>>>(d_out, (long)out_size * 2);
    return;
  }

  int* flags = (int*)(ws + o_flags);
  float* BF  = ws + o_BF;
  void* BA   = (void*)(ws + o_BA);
  void* BHL  = (void*)(ws + o_BHL);
  void* F1   = BA;
  int* srcv  = (int*)(ws + o_idx);
  int* dstv  = srcv + E;
  int* ideg  = (int*)(ws + o_ideg);
  int* cursor= (int*)(ws + o_cur);
  int* rowp  = (int*)(ws + o_rowp);
  int* csr   = (int*)(ws + o_csr);
  float* dinv= ws + o_dinv;
  float* U   = ws + o_U;
  float* U2  = ws + o_U2;
  float* st  = ws + o_stats;
  unsigned short* Wgt   = (unsigned short*)(ws + o_Wgt);
  unsigned short* W2t   = (unsigned short*)(ws + o_W2t);
  unsigned short* Wft   = (unsigned short*)(ws + o_Wft);
  unsigned short* W1t   = (unsigned short*)(ws + o_W1t);
  unsigned short* Wff2t = (unsigned short*)(ws + o_Wff2t);
  unsigned short* Ut    = (unsigned short*)(ws + o_Ut);
  unsigned short* U2t   = (unsigned short*)(ws + o_U2t);

  detect_kernel<<<1, 64, 0, stream>>>(d_in[0], d_in[1], flags);
  hipMemsetAsync(ws + o_zero, 0, zlen * 4, stream);

  auto cvt = [&](int idx, size_t off, long n){
    int blocks = (int)((n + 255) / 256); if (blocks > 4096) blocks = 4096;
    cvt_f<<<blocks, 256, 0, stream>>>(d_in[idx], ws + off, n, flags);
  };
  cvt(3,  o_filt, KE * TJN);
  cvt(5,  o_bgcn, DD);
  cvt(7,  o_b2,  DD);
  cvt(9,  o_bfus, DD);
  for (int i = 0; i < 6; i++) cvt(10 + i, o_bn + i * DD, DD);
  cvt(17, o_bff1, 2 * DD);
  cvt(19, o_bff2, DD);
  cvt_wt<<<1024, 256, 0, stream>>>(d_in[4],  Wgt,   DD, DD, flags);
  cvt_linW<<<(TJN * DD * 128 + 255) / 256, 256, 0, stream>>>(d_in[6], W2t, flags);
  cvt_wt<<<1024, 256, 0, stream>>>(d_in[8],  Wft,   DD, DD, flags);
  cvt_wt<<<2048, 256, 0, stream>>>(d_in[16], W1t,   DD, 2 * DD, flags);
  cvt_wt<<<2048, 256, 0, stream>>>(d_in[18], Wff2t, 2 * DD, DD, flags);
  cvt_idx<<<4096, 256, 0, stream>>>(d_in[1], srcv, 2L * E, flags);

  // CSR build
  deg_kernel<<<(E + 255) / 256, 256, 0, stream>>>(dstv, ideg, E);
  scan_kernel<<<1, 1024, 0, stream>>>(ideg, rowp, E);
  dinv_kernel<<<(NN + 255) / 256, 256, 0, stream>>>(ideg, dinv);
  scatter_kernel<<<(E + 255) / 256, 256, 0, stream>>>(srcv, dstv, rowp, cursor, csr, E);

  const int MT = (NN + 127) / 128;   // 391
  dim3 blk(256);
  const void* Xr  = d_in[0];
  const void* EVr = d_in[2];

  // ---- local GCN branch ----
  gemm_mfma<<<dim3(4, MT), blk, 0, stream>>>(Xr, Wgt, BA, NN, DD, DD, DD, DD,
                                             nullptr, nullptr, 0, 2, 0, 1, flags);   // xw bf16
  gcn_gather<<<NN, 64, 0, stream>>>(rowp, csr, dinv, BA, Xr, ws + o_bgcn, BF, flags);
  bn_stats<<<MT, 512, 0, stream>>>(BF, st + 0, st + DD);
  bn_apply<<<4096, 256, 0, stream>>>(BF, st + 0, st + DD,
                                     ws + o_bn + 0 * DD, ws + o_bn + 1 * DD,
                                     nullptr, 0, BHL, 1, flags);                     // h_local bf16

  // ---- global WaveGC branch ----
  gemm_mfma<<<dim3(4, MT), blk, 0, stream>>>(Xr, W2t, BA, NN, DD, DD, DD, DD,
                                             ws + o_b2, nullptr, 0, 2, 0, 1, flags); // HT bf16
  sgemm_tn_atomic<<<dim3(4, 4, 25), blk, 0, stream>>>(EVr, BA, U, NN, KE, DD, DD,
                                                      2048, 2, 1, flags);
  scale_sig_t<<<(KE * DD) / 256, 256, 0, stream>>>(U, ws + o_filt, Ut);
  gemm_mfma<<<dim3(4, MT), blk, 0, stream>>>(EVr, Ut, BA, NN, DD, KE, KE, DD,
                                             nullptr, nullptr, 1, 2, 0, 1, flags);   // V bf16
  sgemm_tn_atomic<<<dim3(4, 4, 25), blk, 0, stream>>>(EVr, BA, U2, NN, KE, DD, DD,
                                                      2048, 2, 1, flags);
  scale_sig_t<<<(KE * DD) / 256, 256, 0, stream>>>(U2, ws + o_filt, U2t);
  gemm_mfma<<<dim3(4, MT), blk, 0, stream>>>(EVr, U2t, BA, NN, DD, KE, KE, DD,
                                             nullptr, nullptr, 0, 2, 0, 1, flags);   // COMB bf16
  gemm_mfma<<<dim3(4, MT), blk, 0, stream>>>(BA, Wft, BF, NN, DD, DD, DD, DD,
                                             ws + o_bfus, Xr, 1, 1, 2, 0, flags);    // relu+X fp32
  bn_stats<<<MT, 512, 0, stream>>>(BF, st + 2 * DD, st + 3 * DD);
  bn_apply<<<4096, 256, 0, stream>>>(BF, st + 2 * DD, st + 3 * DD,
                                     ws + o_bn + 2 * DD, ws + o_bn + 3 * DD,
                                     BHL, 1, BF, 0, flags);                          // h fp32 in-place

  // ---- FFN ----
  gemm_mfma<<<dim3(8, MT), blk, 0, stream>>>(BF, W1t, F1, NN, 2 * DD, DD, DD, 2 * DD,
                                             ws + o_bff1, nullptr, 1, 0, 0, 1, flags); // F1 bf16
  gemm_mfma<<<dim3(4, MT), blk, 0, stream>>>(F1, Wff2t, BF, NN, DD, 2 * DD, 2 * DD, DD,
                                             ws + o_bff2, BF, 0, 1, 0, 0, flags);    // ff2 + h
  bn_stats<<<MT, 512, 0, stream>>>(BF, st + 4 * DD, st + 5 * DD);
  bn_apply<<<4096, 256, 0, stream>>>(BF, st + 4 * DD, st + 5 * DD,
                                     ws + o_bn + 4 * DD, ws + o_bn + 5 * DD,
                                     nullptr, 0, d_out, 2, flags);                   // -> out
}